// Round 20
// baseline (214.738 us; speedup 1.0000x reference)
//
#include <hip/hip_runtime.h>
#include <cmath>

// ---------------------------------------------------------------------------
// Swin block, MI355X. Pipeline (all fp16 MFMA GEMMs, fp32 accum):
//   pre (casts+gather) -> qkv GEMM (gemmb) -> attention -> out-proj GEMM ->
//   LN1 -> FFN1 GEMM+GELU (gemmb) -> FFN2 GEMM -> LN2+unpartition
// gemmb (R20): BK=32 DOUBLE-buffer (2x16KB = 32KB -> keeps 3 blocks/CU, the
//   R9/R11-proven lever) + R16's drain-hiding order (stage(t+1) first, then
//   reads+MFMA, then vmcnt(0)+barrier landing AFTER the MFMA window).
//   ONE barrier/tile. The only untested cell combining both proven wins.
// gemml (R15-proven) for out-proj (BN=64,MREP=2) and FFN2 (BN=64,MREP=4).
// Ledger (do not retry): deep-pipe 1-blk/CU (R4/5/6/7/14/16@BK64),
//   launch_bounds(256,8) spill (R10), 64^2 tiles (R12), A-in-regs (R17).
// ---------------------------------------------------------------------------

typedef _Float16 half8 __attribute__((ext_vector_type(8)));
typedef _Float16 half4v __attribute__((ext_vector_type(4)));
typedef float f32x4 __attribute__((ext_vector_type(4)));

#define GLOBAL_AS(p) ((const __attribute__((address_space(1))) void*)(p))
#define LDS_AS(p) ((__attribute__((address_space(3))) void*)(p))

__device__ __forceinline__ void gload_lds16(const _Float16* g, _Float16* l) {
  __builtin_amdgcn_global_load_lds(GLOBAL_AS(g), LDS_AS(l), 16, 0, 0);
}

__device__ __forceinline__ float wave_sum(float v) {
#pragma unroll
  for (int off = 32; off > 0; off >>= 1) v += __shfl_xor(v, off, 64);
  return v;
}

// tanh-form GELU, branch-free. |err| vs exact erf-GELU < 3e-3 (validated R3-R19).
__device__ __forceinline__ float gelu_fast(float x) {
  const float y = 1.5957691216057308f * (x + 0.044715f * x * x * x);
  const float e = __expf(y);
  const float t = 1.0f - 2.0f / (e + 1.0f);
  return 0.5f * x * (1.0f + t);
}

// ---- fused pre-pass: window-gather/cast of x + 4 weight casts --------------
__global__ __launch_bounds__(256) void pre_kernel(
    const float* __restrict__ x, _Float16* __restrict__ xw,
    const float* __restrict__ s0, _Float16* __restrict__ d0,
    const float* __restrict__ s1, _Float16* __restrict__ d1,
    const float* __restrict__ s2, _Float16* __restrict__ d2,
    const float* __restrict__ s3, _Float16* __restrict__ d3) {
  int b = blockIdx.x;
  if (b < 4096) {
    const int idx = b * 256 + threadIdx.x;
    const int t = idx >> 6;
    const int e0 = (idx & 63) << 3;
    const int l = t >> 6, n = t & 63;
    const int bb = l >> 6, wh = (l >> 3) & 7, ww = l & 7;
    const int pi = n >> 3, pj = n & 7;
    const int xrow = (bb * 4096 + (wh * 8 + pi) * 64 + (ww * 8 + pj)) * 512;
    const float4 a = *(const float4*)&x[xrow + e0];
    const float4 c = *(const float4*)&x[xrow + e0 + 4];
    half8 o;
    o[0] = (_Float16)a.x; o[1] = (_Float16)a.y; o[2] = (_Float16)a.z; o[3] = (_Float16)a.w;
    o[4] = (_Float16)c.x; o[5] = (_Float16)c.y; o[6] = (_Float16)c.z; o[7] = (_Float16)c.w;
    *(half8*)&xw[t * 512 + e0] = o;
    return;
  }
  b -= 4096;
  const float* s; _Float16* d;
  if (b < 768) { s = s0; d = d0; }
  else if (b < 1024) { s = s1; d = d1; b -= 768; }
  else if (b < 2048) { s = s2; d = d2; b -= 1024; }
  else { s = s3; d = d3; b -= 2048; }
  const int i = (b * 256 + threadIdx.x) * 4;
  const float4 v = *(const float4*)&s[i];
  half4v o;
  o[0] = (_Float16)v.x; o[1] = (_Float16)v.y; o[2] = (_Float16)v.z; o[3] = (_Float16)v.w;
  *(half4v*)&d[i] = o;
}

// ---- gemmb: 128x128, BK=32, 2x16KB dbuf, drain-hidden, C = A@B^T + bias ----
// 4 waves 2x2, acc[4][4], 16 MFMA/wave/tile. Per tile: issue stage(t+1) into
// the other buffer FIRST, then 8 ds_read_b128 + 16 MFMA on tile t, then
// vmcnt(0)+lgkm(0)+s_barrier (drain lands after the MFMA window; the barrier
// simultaneously retires reads of buf p so t+2 may stage into it).
// 64B rows (4 slots): phys slot p = s ^ ((row>>1)&3); inverse on global src.
template <int EPI, int K>
__global__ __launch_bounds__(256, 4) void gemmb_kernel(
    const _Float16* __restrict__ A, const _Float16* __restrict__ B,
    const float* __restrict__ bias, _Float16* __restrict__ C, int N) {
  constexpr int NT = K / 32;
  constexpr int TA = 128 * 32;        // 4096 elems = 8 KB
  constexpr int TT = 2 * TA;          // A + B per buffer
  __shared__ _Float16 L[2][TT];       // 32 KB total

  const int tid = threadIdx.x, lane = tid & 63, wave = tid >> 6;
  const int wr = wave >> 1, wc = wave & 1;
  const int lr = lane & 15, g = lane >> 4;

  const int nbn = N >> 7;
  const int cpx = gridDim.x >> 3;
  const int wg = (blockIdx.x & 7) * cpx + (blockIdx.x >> 3);
  const int bm = wg / nbn, bn = wg % nbn;

  // staging: one gload = 16 rows x 32 cols. lane -> (srow=lane>>2, pslot=lane&3)
  // source col slot = pslot ^ ((lane>>3)&3)  [inverse of p = s ^ ((row>>1)&3)]
  const int scol = (((lane & 3) ^ ((lane >> 3) & 3)) << 3);
  const int srow = lane >> 2;
  const _Float16* aS = A + (size_t)(bm * 128 + wave * 16 + srow) * K + scol;
  const _Float16* bS = B + (size_t)(bn * 128 + wave * 16 + srow) * K + scol;

  auto stage = [&](int b, int t) {
    const int koff = t * 32;
    gload_lds16(aS + koff, &L[b][(wave * 16) * 32]);
    gload_lds16(aS + (size_t)64 * K + koff, &L[b][(64 + wave * 16) * 32]);
    gload_lds16(bS + koff, &L[b][TA + (wave * 16) * 32]);
    gload_lds16(bS + (size_t)64 * K + koff, &L[b][TA + (64 + wave * 16) * 32]);
  };

  // fragment reads: logical slot g, phys slot g ^ ((lr>>1)&3) (row>>1 ≡ lr>>1 mod 4)
  const int sw = ((g ^ ((lr >> 1) & 3)) << 3);
  int arow[4], brow[4];
#pragma unroll
  for (int m = 0; m < 4; ++m) arow[m] = (wr * 64 + m * 16 + lr) * 32 + sw;
#pragma unroll
  for (int n = 0; n < 4; ++n) brow[n] = TA + (wc * 64 + n * 16 + lr) * 32 + sw;

  f32x4 acc[4][4] = {};

  stage(0, 0);
  asm volatile("s_waitcnt vmcnt(0)" ::: "memory");
  asm volatile("s_barrier" ::: "memory");

#pragma unroll 4
  for (int t = 0; t < NT; ++t) {
    const int p = t & 1;
    if (t + 1 < NT) stage(p ^ 1, t + 1);  // issue prefetch FIRST
    const _Float16* Lp = &L[p][0];
    half8 af[4], bf[4];
#pragma unroll
    for (int m = 0; m < 4; ++m) af[m] = *(const half8*)&Lp[arow[m]];
#pragma unroll
    for (int n = 0; n < 4; ++n) bf[n] = *(const half8*)&Lp[brow[n]];
#pragma unroll
    for (int m = 0; m < 4; ++m)
#pragma unroll
      for (int n = 0; n < 4; ++n)
        acc[m][n] = __builtin_amdgcn_mfma_f32_16x16x32_f16(af[m], bf[n], acc[m][n], 0, 0, 0);
    // drain lands AFTER the MFMA window; barrier also retires reads of buf p
    asm volatile("s_waitcnt vmcnt(0) lgkmcnt(0)" ::: "memory");
    asm volatile("s_barrier" ::: "memory");
  }

  // epilogue: bias(+GELU), per-wave LDS transpose, 16B-contiguous stores
  float bsv[4];
#pragma unroll
  for (int n = 0; n < 4; ++n) bsv[n] = bias[bn * 128 + wc * 64 + n * 16 + lr];
  _Float16* Lc = &L[0][0] + wave * 4096;  // 64 rows x 64 cols per wave
#pragma unroll
  for (int m = 0; m < 4; ++m)
#pragma unroll
    for (int n = 0; n < 4; ++n)
#pragma unroll
      for (int r = 0; r < 4; ++r) {
        float v = acc[m][n][r] + bsv[n];
        if (EPI == 1) v = gelu_fast(v);
        const int row = m * 16 + g * 4 + r;
        const int col = n * 16 + lr;
        Lc[row * 64 + (col ^ ((row & 7) << 3))] = (_Float16)v;
      }
  asm volatile("s_waitcnt lgkmcnt(0)" ::: "memory");
  const int rrow = lane >> 3, slot = lane & 7;
  const int growb = bm * 128 + wr * 64;
  const int gcol = bn * 128 + wc * 64 + slot * 8;
#pragma unroll
  for (int blk = 0; blk < 8; ++blk) {
    const int row = blk * 8 + rrow;
    const half8 vv = *(const half8*)&Lc[row * 64 + ((slot ^ (row & 7)) << 3)];
    *(half8*)&C[(size_t)(growb + row) * N + gcol] = vv;
  }
}

// ---- gemml (R15-proven): BM x BN, BK=64, 4 waves, single LDS buffer --------
template <int EPI, int K, int BN, int MREP>
__global__ __launch_bounds__(256, 4) void gemml_kernel(
    const _Float16* __restrict__ A, const _Float16* __restrict__ B,
    const float* __restrict__ bias, _Float16* __restrict__ C, int N) {
  constexpr int NT = K / 64;
  constexpr int NWR = (BN == 128) ? 2 : 4;
  constexpr int BM = NWR * MREP * 16;
  constexpr int TA = BM * 64;
  constexpr int TB = BN * 64;
  __shared__ _Float16 L[TA + TB];

  const int tid = threadIdx.x, lane = tid & 63, wave = tid >> 6;
  const int wr = (BN == 128) ? (wave >> 1) : wave;
  const int wc = (BN == 128) ? (wave & 1) : 0;
  const int lr = lane & 15, g = lane >> 4;

  const int nbn = N / BN;
  const int cpx = gridDim.x >> 3;
  const int wg = (blockIdx.x & 7) * cpx + (blockIdx.x >> 3);
  const int bm = wg / nbn, bn = wg % nbn;

  const int scol = ((lane & 7) ^ (lane >> 3)) << 3;
  const int srow = lane >> 3;
  const _Float16* aS = A + (size_t)(bm * BM + wave * 8 + srow) * K + scol;
  const _Float16* bS = B + (size_t)(bn * BN + wave * 8 + srow) * K + scol;

  const int sw0 = ((g ^ (lr & 7)) << 3);
  const int sw1 = (((4 + g) ^ (lr & 7)) << 3);
  int arow[MREP], brow[4];
#pragma unroll
  for (int m = 0; m < MREP; ++m) arow[m] = (wr * (MREP * 16) + m * 16 + lr) * 64;
#pragma unroll
  for (int n = 0; n < 4; ++n) brow[n] = TA + (wc * 64 + n * 16 + lr) * 64;

  f32x4 acc[MREP][4] = {};

#pragma unroll 8
  for (int t = 0; t < NT; ++t) {
    const int koff = t * 64;
#pragma unroll
    for (int i = 0; i < BM / 32; ++i)
      gload_lds16(aS + (size_t)(i * 32) * K + koff, &L[(i * 32 + wave * 8) * 64]);
#pragma unroll
    for (int i = 0; i < BN / 32; ++i)
      gload_lds16(bS + (size_t)(i * 32) * K + koff, &L[TA + (i * 32 + wave * 8) * 64]);
    __syncthreads();
    half8 af[MREP], bf[4];
#pragma unroll
    for (int m = 0; m < MREP; ++m) af[m] = *(const half8*)&L[arow[m] + sw0];
#pragma unroll
    for (int n = 0; n < 4; ++n) bf[n] = *(const half8*)&L[brow[n] + sw0];
    __builtin_amdgcn_s_setprio(1);
#pragma unroll
    for (int m = 0; m < MREP; ++m)
#pragma unroll
      for (int n = 0; n < 4; ++n)
        acc[m][n] = __builtin_amdgcn_mfma_f32_16x16x32_f16(af[m], bf[n], acc[m][n], 0, 0, 0);
    __builtin_amdgcn_s_setprio(0);
#pragma unroll
    for (int m = 0; m < MREP; ++m) af[m] = *(const half8*)&L[arow[m] + sw1];
#pragma unroll
    for (int n = 0; n < 4; ++n) bf[n] = *(const half8*)&L[brow[n] + sw1];
    __builtin_amdgcn_s_setprio(1);
#pragma unroll
    for (int m = 0; m < MREP; ++m)
#pragma unroll
      for (int n = 0; n < 4; ++n)
        acc[m][n] = __builtin_amdgcn_mfma_f32_16x16x32_f16(af[m], bf[n], acc[m][n], 0, 0, 0);
    __builtin_amdgcn_s_setprio(0);
    __syncthreads();
  }

  float bsv[4];
#pragma unroll
  for (int n = 0; n < 4; ++n) bsv[n] = bias[bn * BN + wc * 64 + n * 16 + lr];
  _Float16* Lc = &L[0] + wave * (MREP * 16 * 64);
#pragma unroll
  for (int m = 0; m < MREP; ++m)
#pragma unroll
    for (int n = 0; n < 4; ++n)
#pragma unroll
      for (int r = 0; r < 4; ++r) {
        float v = acc[m][n][r] + bsv[n];
        if (EPI == 1) v = gelu_fast(v);
        const int row = m * 16 + g * 4 + r;
        const int col = n * 16 + lr;
        Lc[row * 64 + (col ^ ((row & 7) << 3))] = (_Float16)v;
      }
  asm volatile("s_waitcnt lgkmcnt(0)" ::: "memory");
  const int rrow = lane >> 3, slot = lane & 7;
  const int growb = bm * BM + wr * (MREP * 16);
  const int gcol = bn * BN + wc * 64 + slot * 8;
#pragma unroll
  for (int blk = 0; blk < MREP * 2; ++blk) {
    const int row = blk * 8 + rrow;
    const half8 vv = *(const half8*)&Lc[row * 64 + ((slot ^ (row & 7)) << 3)];
    *(half8*)&C[(size_t)(growb + row) * N + gcol] = vv;
  }
}

// ---- attention (R19): per (n,h) 256x256x32 flash block, barrier-light ------
__global__ __launch_bounds__(256) void attn_kernel(const _Float16* __restrict__ qkv,
                                                   _Float16* __restrict__ o_out) {
  const int n = blockIdx.x & 63;
  const int h = blockIdx.x >> 6;
  __shared__ _Float16 Ksh[256 * 32];   // swizzled
  __shared__ _Float16 Vt[32 * 264];
  __shared__ _Float16 Pw[4 * 32 * 72]; // per-wave half-P (2 q-tiles)
  const int tid = threadIdx.x;
  const int wq = tid >> 6, lane = tid & 63;
  const int lr = lane & 15, g = lane >> 4;
  const int hq = h * 32;

#pragma unroll
  for (int pass = 0; pass < 4; ++pass) {
    const int e = pass * 2048 + tid * 8;
    const int m = e >> 5, d = e & 31;
    const int base = (m * 64 + n) * 1536 + hq;
    const half8 k8 = *(const half8*)&qkv[base + 512 + d];
    const half8 v8 = *(const half8*)&qkv[base + 1024 + d];
    *(half8*)&Ksh[m * 32 + (((d >> 3) ^ ((m >> 1) & 3)) << 3)] = k8;
#pragma unroll
    for (int j = 0; j < 8; ++j) Vt[(d + j) * 264 + m] = v8[j];
  }
  half8 qf[4];
#pragma unroll
  for (int qt = 0; qt < 4; ++qt) {
    const int qg = wq * 64 + qt * 16 + lr;
    qf[qt] = *(const half8*)&qkv[(qg * 64 + n) * 1536 + hq + g * 8];
  }
  __syncthreads();  // staging visible to all waves (the ONLY barrier)

  f32x4 o[4][2] = {};
  float den[4] = {0.f, 0.f, 0.f, 0.f};
  const float scale = 0.17677669529663687f;  // 1/sqrt(32)
  _Float16* P = &Pw[wq * (32 * 72)];
  const int kswz = ((g ^ ((lr >> 1) & 3)) << 3);

  for (int it = 0; it < 4; ++it) {
    const int k0 = it * 64;
#pragma unroll
    for (int qh = 0; qh < 2; ++qh) {
#pragma unroll
      for (int qt2 = 0; qt2 < 2; ++qt2) {
        const int qt = qh * 2 + qt2;
#pragma unroll
        for (int kt = 0; kt < 4; ++kt) {
          const half8 kf = *(const half8*)&Ksh[(k0 + kt * 16 + lr) * 32 + kswz];
          const f32x4 z = {0.f, 0.f, 0.f, 0.f};
          f32x4 st = __builtin_amdgcn_mfma_f32_16x16x32_f16(kf, qf[qt], z, 0, 0, 0);
          const float p0 = __expf(st[0] * scale);
          const float p1 = __expf(st[1] * scale);
          const float p2 = __expf(st[2] * scale);
          const float p3 = __expf(st[3] * scale);
          den[qt] += (p0 + p1) + (p2 + p3);
          half4v w;
          w[0] = (_Float16)p0; w[1] = (_Float16)p1;
          w[2] = (_Float16)p2; w[3] = (_Float16)p3;
          *(half4v*)&P[(qt2 * 16 + lr) * 72 + kt * 16 + g * 4] = w;
        }
      }
#pragma unroll
      for (int qt2 = 0; qt2 < 2; ++qt2) {
        const int qt = qh * 2 + qt2;
#pragma unroll
        for (int ks = 0; ks < 2; ++ks) {
          const half8 pf = *(const half8*)&P[(qt2 * 16 + lr) * 72 + ks * 32 + g * 8];
#pragma unroll
          for (int dt = 0; dt < 2; ++dt) {
            const half8 vf = *(const half8*)&Vt[(dt * 16 + lr) * 264 + k0 + ks * 32 + g * 8];
            o[qt][dt] = __builtin_amdgcn_mfma_f32_16x16x32_f16(pf, vf, o[qt][dt], 0, 0, 0);
          }
        }
      }
    }
  }

#pragma unroll
  for (int qt = 0; qt < 4; ++qt) {
    float dq = den[qt];
    dq += __shfl_xor(dq, 16);
    dq += __shfl_xor(dq, 32);
    const float inv = 1.0f / dq;
#pragma unroll
    for (int r = 0; r < 4; ++r) {
      const float invr = __shfl(inv, g * 4 + r);
      const int qg = wq * 64 + qt * 16 + g * 4 + r;
      const int obase = (qg * 64 + n) * 512 + hq;
#pragma unroll
      for (int dt = 0; dt < 2; ++dt)
        o_out[obase + dt * 16 + lr] = (_Float16)(o[qt][dt][r] * invr);
    }
  }
}

// ---- LayerNorm over E=512; 1 wave per token, 4 tokens per block ------------
template <int FINAL>
__global__ __launch_bounds__(256) void ln_kernel(
    const _Float16* res16, const _Float16* __restrict__ add16,
    const float* __restrict__ g, const float* __restrict__ b,
    float* __restrict__ out32, _Float16* out16) {
  const int t = blockIdx.x * 4 + (threadIdx.x >> 6);
  const int lane = threadIdx.x & 63;
  const int e0 = lane << 3;
  const int trow = t * 512;
  const half8 a8 = *(const half8*)&add16[trow + e0];
  const half8 r8 = *(const half8*)&res16[trow + e0];
  float v[8];
#pragma unroll
  for (int e = 0; e < 8; ++e) v[e] = (float)r8[e] + (float)a8[e];
  float sm = 0.f;
#pragma unroll
  for (int e = 0; e < 8; ++e) sm += v[e];
  sm = wave_sum(sm);
  const float mu = sm * (1.0f / 512.0f);
  float vs = 0.f;
#pragma unroll
  for (int e = 0; e < 8; ++e) { const float d = v[e] - mu; vs += d * d; }
  vs = wave_sum(vs);
  const float rstd = rsqrtf(vs * (1.0f / 512.0f) + 1e-5f);
  const float4 g1 = *(const float4*)&g[e0];
  const float4 g2 = *(const float4*)&g[e0 + 4];
  const float4 b1 = *(const float4*)&b[e0];
  const float4 b2 = *(const float4*)&b[e0 + 4];
  float y[8];
  y[0] = (v[0] - mu) * rstd * g1.x + b1.x; y[1] = (v[1] - mu) * rstd * g1.y + b1.y;
  y[2] = (v[2] - mu) * rstd * g1.z + b1.z; y[3] = (v[3] - mu) * rstd * g1.w + b1.w;
  y[4] = (v[4] - mu) * rstd * g2.x + b2.x; y[5] = (v[5] - mu) * rstd * g2.y + b2.y;
  y[6] = (v[6] - mu) * rstd * g2.z + b2.z; y[7] = (v[7] - mu) * rstd * g2.w + b2.w;
  if (FINAL) {
    const int l = t >> 6, n = t & 63;
    const int bb = l >> 6, wh = (l >> 3) & 7, ww = l & 7;
    const int pi = n >> 3, pj = n & 7;
    const int xrow = (bb * 4096 + (wh * 8 + pi) * 64 + (ww * 8 + pj)) * 512;
    *(float4*)&out32[xrow + e0] = make_float4(y[0], y[1], y[2], y[3]);
    *(float4*)&out32[xrow + e0 + 4] = make_float4(y[4], y[5], y[6], y[7]);
  } else {
    half8 o16;
#pragma unroll
    for (int e = 0; e < 8; ++e) o16[e] = (_Float16)y[e];
    *(half8*)&out16[trow + e0] = o16;
  }
}

// ---------------------------------------------------------------------------
extern "C" void kernel_launch(void* const* d_in, const int* in_sizes, int n_in,
                              void* d_out, int out_size, void* d_ws, size_t ws_size,
                              hipStream_t stream) {
  const float* x    = (const float*)d_in[0];
  const float* ipw  = (const float*)d_in[1];
  const float* ipb  = (const float*)d_in[2];
  const float* outw = (const float*)d_in[3];
  const float* outb = (const float*)d_in[4];
  const float* ln1g = (const float*)d_in[5];
  const float* ln1b = (const float*)d_in[6];
  const float* w1   = (const float*)d_in[7];
  const float* b1   = (const float*)d_in[8];
  const float* w2   = (const float*)d_in[9];
  const float* b2   = (const float*)d_in[10];
  const float* ln2g = (const float*)d_in[11];
  const float* ln2b = (const float*)d_in[12];
  float* out = (float*)d_out;
  char* ws = (char*)d_ws;

  _Float16* wqkv_h = (_Float16*)(ws + 0);          // 1536x512
  _Float16* wout_h = (_Float16*)(ws + 1572864);    // 512x512
  _Float16* w1_h   = (_Float16*)(ws + 2097152);    // 2048x512
  _Float16* w2_h   = (_Float16*)(ws + 4194304);    // 512x2048
  _Float16* xw_h   = (_Float16*)(ws + 6291456);    // 16384x512  (reused: y16)
  _Float16* qkv_h  = (_Float16*)(ws + 23068672);   // 16384x1536 (reused: h 16384x2048)
  _Float16* attn_h = (_Float16*)(ws + 90177536);   // 16384x512  (reused: f)
  _Float16* ao_h   = (_Float16*)(ws + 106954752);  // 16384x512
  _Float16* h_h = qkv_h;
  _Float16* f_h = attn_h;
  _Float16* y16 = xw_h;

  pre_kernel<<<7168, 256, 0, stream>>>(x, xw_h, ipw, wqkv_h, outw, wout_h,
                                       w1, w1_h, w2, w2_h);
  gemmb_kernel<0, 512><<<1536, 256, 0, stream>>>(xw_h, wqkv_h, ipb, qkv_h, 1536);
  attn_kernel<<<1024, 256, 0, stream>>>(qkv_h, attn_h);
  gemml_kernel<0, 512, 64, 2><<<1024, 256, 0, stream>>>(attn_h, wout_h, outb, ao_h, 512);
  ln_kernel<0><<<4096, 256, 0, stream>>>(xw_h, ao_h, ln1g, ln1b, nullptr, y16);
  gemmb_kernel<1, 512><<<2048, 256, 0, stream>>>(y16, w1_h, b1, h_h, 2048);
  gemml_kernel<0, 2048, 64, 4><<<512, 256, 0, stream>>>(h_h, w2_h, b2, f_h, 512);
  ln_kernel<1><<<4096, 256, 0, stream>>>(y16, f_h, ln2g, ln2b, out, nullptr);
}

// Round 21
// 201.142 us; speedup vs baseline: 1.0676x; 1.0676x over previous
//
#include <hip/hip_runtime.h>
#include <cmath>

// ---------------------------------------------------------------------------
// Swin block, MI355X — FINAL configuration (best measured: R19, 201.76 us).
//   pre (casts+gather) -> qkv GEMM -> attention -> out-proj GEMM -> LN1 ->
//   FFN1 GEMM+GELU -> FFN2 GEMM -> LN2+unpartition
// gemml: BM x BN tile, BK=64, 4 waves, single 24-32KB LDS buffer, m97
//   2-sync loop, ~3 blocks/CU co-residency (the only lever that ever paid:
//   R9 +14%). Conflict-free XOR swizzle, 16B gload_lds, transposed 16B-
//   contiguous epilogue stores, XCD-chunked grid swizzle.
// attn: barrier-light MFMA flash (P wave-private), 51.7KB LDS.
// Structural plateau evidence (13 GEMM variants, FFN1 74-130us):
//   barrier granularity 1/2/9 per tile, 1/2/3 buffers, tiles 64^2..256^2,
//   BK 32/64, 1/2/3/8 blocks/CU, LDS/reg staging -> all >= this config.
//   All pipes <45% (latency-bound at register-capped occupancy).
// ---------------------------------------------------------------------------

typedef _Float16 half8 __attribute__((ext_vector_type(8)));
typedef _Float16 half4v __attribute__((ext_vector_type(4)));
typedef float f32x4 __attribute__((ext_vector_type(4)));

#define GLOBAL_AS(p) ((const __attribute__((address_space(1))) void*)(p))
#define LDS_AS(p) ((__attribute__((address_space(3))) void*)(p))

__device__ __forceinline__ void gload_lds16(const _Float16* g, _Float16* l) {
  __builtin_amdgcn_global_load_lds(GLOBAL_AS(g), LDS_AS(l), 16, 0, 0);
}

__device__ __forceinline__ float wave_sum(float v) {
#pragma unroll
  for (int off = 32; off > 0; off >>= 1) v += __shfl_xor(v, off, 64);
  return v;
}

// tanh-form GELU, branch-free. |err| vs exact erf-GELU < 3e-3 (validated R3-R20).
__device__ __forceinline__ float gelu_fast(float x) {
  const float y = 1.5957691216057308f * (x + 0.044715f * x * x * x);
  const float e = __expf(y);
  const float t = 1.0f - 2.0f / (e + 1.0f);
  return 0.5f * x * (1.0f + t);
}

// ---- fused pre-pass: window-gather/cast of x + 4 weight casts --------------
__global__ __launch_bounds__(256) void pre_kernel(
    const float* __restrict__ x, _Float16* __restrict__ xw,
    const float* __restrict__ s0, _Float16* __restrict__ d0,
    const float* __restrict__ s1, _Float16* __restrict__ d1,
    const float* __restrict__ s2, _Float16* __restrict__ d2,
    const float* __restrict__ s3, _Float16* __restrict__ d3) {
  int b = blockIdx.x;
  if (b < 4096) {
    const int idx = b * 256 + threadIdx.x;
    const int t = idx >> 6;
    const int e0 = (idx & 63) << 3;
    const int l = t >> 6, n = t & 63;
    const int bb = l >> 6, wh = (l >> 3) & 7, ww = l & 7;
    const int pi = n >> 3, pj = n & 7;
    const int xrow = (bb * 4096 + (wh * 8 + pi) * 64 + (ww * 8 + pj)) * 512;
    const float4 a = *(const float4*)&x[xrow + e0];
    const float4 c = *(const float4*)&x[xrow + e0 + 4];
    half8 o;
    o[0] = (_Float16)a.x; o[1] = (_Float16)a.y; o[2] = (_Float16)a.z; o[3] = (_Float16)a.w;
    o[4] = (_Float16)c.x; o[5] = (_Float16)c.y; o[6] = (_Float16)c.z; o[7] = (_Float16)c.w;
    *(half8*)&xw[t * 512 + e0] = o;
    return;
  }
  b -= 4096;
  const float* s; _Float16* d;
  if (b < 768) { s = s0; d = d0; }
  else if (b < 1024) { s = s1; d = d1; b -= 768; }
  else if (b < 2048) { s = s2; d = d2; b -= 1024; }
  else { s = s3; d = d3; b -= 2048; }
  const int i = (b * 256 + threadIdx.x) * 4;
  const float4 v = *(const float4*)&s[i];
  half4v o;
  o[0] = (_Float16)v.x; o[1] = (_Float16)v.y; o[2] = (_Float16)v.z; o[3] = (_Float16)v.w;
  *(half4v*)&d[i] = o;
}

// ---- gemml: C[M,N] = A[M,K] @ B[N,K]^T + bias (R15-proven) -----------------
template <int EPI, int K, int BN, int MREP>
__global__ __launch_bounds__(256, 4) void gemml_kernel(
    const _Float16* __restrict__ A, const _Float16* __restrict__ B,
    const float* __restrict__ bias, _Float16* __restrict__ C, int N) {
  constexpr int NT = K / 64;
  constexpr int NWR = (BN == 128) ? 2 : 4;
  constexpr int BM = NWR * MREP * 16;
  constexpr int TA = BM * 64;
  constexpr int TB = BN * 64;
  __shared__ _Float16 L[TA + TB];

  const int tid = threadIdx.x, lane = tid & 63, wave = tid >> 6;
  const int wr = (BN == 128) ? (wave >> 1) : wave;
  const int wc = (BN == 128) ? (wave & 1) : 0;
  const int lr = lane & 15, g = lane >> 4;

  const int nbn = N / BN;
  const int cpx = gridDim.x >> 3;
  const int wg = (blockIdx.x & 7) * cpx + (blockIdx.x >> 3);
  const int bm = wg / nbn, bn = wg % nbn;

  const int scol = ((lane & 7) ^ (lane >> 3)) << 3;
  const int srow = lane >> 3;
  const _Float16* aS = A + (size_t)(bm * BM + wave * 8 + srow) * K + scol;
  const _Float16* bS = B + (size_t)(bn * BN + wave * 8 + srow) * K + scol;

  const int sw0 = ((g ^ (lr & 7)) << 3);
  const int sw1 = (((4 + g) ^ (lr & 7)) << 3);
  int arow[MREP], brow[4];
#pragma unroll
  for (int m = 0; m < MREP; ++m) arow[m] = (wr * (MREP * 16) + m * 16 + lr) * 64;
#pragma unroll
  for (int n = 0; n < 4; ++n) brow[n] = TA + (wc * 64 + n * 16 + lr) * 64;

  f32x4 acc[MREP][4] = {};

#pragma unroll 8
  for (int t = 0; t < NT; ++t) {
    const int koff = t * 64;
#pragma unroll
    for (int i = 0; i < BM / 32; ++i)
      gload_lds16(aS + (size_t)(i * 32) * K + koff, &L[(i * 32 + wave * 8) * 64]);
#pragma unroll
    for (int i = 0; i < BN / 32; ++i)
      gload_lds16(bS + (size_t)(i * 32) * K + koff, &L[TA + (i * 32 + wave * 8) * 64]);
    __syncthreads();
    half8 af[MREP], bf[4];
#pragma unroll
    for (int m = 0; m < MREP; ++m) af[m] = *(const half8*)&L[arow[m] + sw0];
#pragma unroll
    for (int n = 0; n < 4; ++n) bf[n] = *(const half8*)&L[brow[n] + sw0];
    __builtin_amdgcn_s_setprio(1);
#pragma unroll
    for (int m = 0; m < MREP; ++m)
#pragma unroll
      for (int n = 0; n < 4; ++n)
        acc[m][n] = __builtin_amdgcn_mfma_f32_16x16x32_f16(af[m], bf[n], acc[m][n], 0, 0, 0);
    __builtin_amdgcn_s_setprio(0);
#pragma unroll
    for (int m = 0; m < MREP; ++m) af[m] = *(const half8*)&L[arow[m] + sw1];
#pragma unroll
    for (int n = 0; n < 4; ++n) bf[n] = *(const half8*)&L[brow[n] + sw1];
    __builtin_amdgcn_s_setprio(1);
#pragma unroll
    for (int m = 0; m < MREP; ++m)
#pragma unroll
      for (int n = 0; n < 4; ++n)
        acc[m][n] = __builtin_amdgcn_mfma_f32_16x16x32_f16(af[m], bf[n], acc[m][n], 0, 0, 0);
    __builtin_amdgcn_s_setprio(0);
    __syncthreads();
  }

  float bsv[4];
#pragma unroll
  for (int n = 0; n < 4; ++n) bsv[n] = bias[bn * BN + wc * 64 + n * 16 + lr];
  _Float16* Lc = &L[0] + wave * (MREP * 16 * 64);
#pragma unroll
  for (int m = 0; m < MREP; ++m)
#pragma unroll
    for (int n = 0; n < 4; ++n)
#pragma unroll
      for (int r = 0; r < 4; ++r) {
        float v = acc[m][n][r] + bsv[n];
        if (EPI == 1) v = gelu_fast(v);
        const int row = m * 16 + g * 4 + r;
        const int col = n * 16 + lr;
        Lc[row * 64 + (col ^ ((row & 7) << 3))] = (_Float16)v;
      }
  asm volatile("s_waitcnt lgkmcnt(0)" ::: "memory");
  const int rrow = lane >> 3, slot = lane & 7;
  const int growb = bm * BM + wr * (MREP * 16);
  const int gcol = bn * BN + wc * 64 + slot * 8;
#pragma unroll
  for (int blk = 0; blk < MREP * 2; ++blk) {
    const int row = blk * 8 + rrow;
    const half8 vv = *(const half8*)&Lc[row * 64 + ((slot ^ (row & 7)) << 3)];
    *(half8*)&C[(size_t)(growb + row) * N + gcol] = vv;
  }
}

// ---- attention (R19): per (n,h) 256x256x32 flash block, barrier-light ------
__global__ __launch_bounds__(256) void attn_kernel(const _Float16* __restrict__ qkv,
                                                   _Float16* __restrict__ o_out) {
  const int n = blockIdx.x & 63;
  const int h = blockIdx.x >> 6;
  __shared__ _Float16 Ksh[256 * 32];   // swizzled
  __shared__ _Float16 Vt[32 * 264];
  __shared__ _Float16 Pw[4 * 32 * 72]; // per-wave half-P (2 q-tiles)
  const int tid = threadIdx.x;
  const int wq = tid >> 6, lane = tid & 63;
  const int lr = lane & 15, g = lane >> 4;
  const int hq = h * 32;

#pragma unroll
  for (int pass = 0; pass < 4; ++pass) {
    const int e = pass * 2048 + tid * 8;
    const int m = e >> 5, d = e & 31;
    const int base = (m * 64 + n) * 1536 + hq;
    const half8 k8 = *(const half8*)&qkv[base + 512 + d];
    const half8 v8 = *(const half8*)&qkv[base + 1024 + d];
    *(half8*)&Ksh[m * 32 + (((d >> 3) ^ ((m >> 1) & 3)) << 3)] = k8;
#pragma unroll
    for (int j = 0; j < 8; ++j) Vt[(d + j) * 264 + m] = v8[j];
  }
  half8 qf[4];
#pragma unroll
  for (int qt = 0; qt < 4; ++qt) {
    const int qg = wq * 64 + qt * 16 + lr;
    qf[qt] = *(const half8*)&qkv[(qg * 64 + n) * 1536 + hq + g * 8];
  }
  __syncthreads();  // staging visible to all waves (the ONLY barrier)

  f32x4 o[4][2] = {};
  float den[4] = {0.f, 0.f, 0.f, 0.f};
  const float scale = 0.17677669529663687f;  // 1/sqrt(32)
  _Float16* P = &Pw[wq * (32 * 72)];
  const int kswz = ((g ^ ((lr >> 1) & 3)) << 3);

  for (int it = 0; it < 4; ++it) {
    const int k0 = it * 64;
#pragma unroll
    for (int qh = 0; qh < 2; ++qh) {
#pragma unroll
      for (int qt2 = 0; qt2 < 2; ++qt2) {
        const int qt = qh * 2 + qt2;
#pragma unroll
        for (int kt = 0; kt < 4; ++kt) {
          const half8 kf = *(const half8*)&Ksh[(k0 + kt * 16 + lr) * 32 + kswz];
          const f32x4 z = {0.f, 0.f, 0.f, 0.f};
          f32x4 st = __builtin_amdgcn_mfma_f32_16x16x32_f16(kf, qf[qt], z, 0, 0, 0);
          const float p0 = __expf(st[0] * scale);
          const float p1 = __expf(st[1] * scale);
          const float p2 = __expf(st[2] * scale);
          const float p3 = __expf(st[3] * scale);
          den[qt] += (p0 + p1) + (p2 + p3);
          half4v w;
          w[0] = (_Float16)p0; w[1] = (_Float16)p1;
          w[2] = (_Float16)p2; w[3] = (_Float16)p3;
          *(half4v*)&P[(qt2 * 16 + lr) * 72 + kt * 16 + g * 4] = w;
        }
      }
#pragma unroll
      for (int qt2 = 0; qt2 < 2; ++qt2) {
        const int qt = qh * 2 + qt2;
#pragma unroll
        for (int ks = 0; ks < 2; ++ks) {
          const half8 pf = *(const half8*)&P[(qt2 * 16 + lr) * 72 + ks * 32 + g * 8];
#pragma unroll
          for (int dt = 0; dt < 2; ++dt) {
            const half8 vf = *(const half8*)&Vt[(dt * 16 + lr) * 264 + k0 + ks * 32 + g * 8];
            o[qt][dt] = __builtin_amdgcn_mfma_f32_16x16x32_f16(pf, vf, o[qt][dt], 0, 0, 0);
          }
        }
      }
    }
  }

#pragma unroll
  for (int qt = 0; qt < 4; ++qt) {
    float dq = den[qt];
    dq += __shfl_xor(dq, 16);
    dq += __shfl_xor(dq, 32);
    const float inv = 1.0f / dq;
#pragma unroll
    for (int r = 0; r < 4; ++r) {
      const float invr = __shfl(inv, g * 4 + r);
      const int qg = wq * 64 + qt * 16 + g * 4 + r;
      const int obase = (qg * 64 + n) * 512 + hq;
#pragma unroll
      for (int dt = 0; dt < 2; ++dt)
        o_out[obase + dt * 16 + lr] = (_Float16)(o[qt][dt][r] * invr);
    }
  }
}

// ---- LayerNorm over E=512; 1 wave per token, 4 tokens per block ------------
template <int FINAL>
__global__ __launch_bounds__(256) void ln_kernel(
    const _Float16* res16, const _Float16* __restrict__ add16,
    const float* __restrict__ g, const float* __restrict__ b,
    float* __restrict__ out32, _Float16* out16) {
  const int t = blockIdx.x * 4 + (threadIdx.x >> 6);
  const int lane = threadIdx.x & 63;
  const int e0 = lane << 3;
  const int trow = t * 512;
  const half8 a8 = *(const half8*)&add16[trow + e0];
  const half8 r8 = *(const half8*)&res16[trow + e0];
  float v[8];
#pragma unroll
  for (int e = 0; e < 8; ++e) v[e] = (float)r8[e] + (float)a8[e];
  float sm = 0.f;
#pragma unroll
  for (int e = 0; e < 8; ++e) sm += v[e];
  sm = wave_sum(sm);
  const float mu = sm * (1.0f / 512.0f);
  float vs = 0.f;
#pragma unroll
  for (int e = 0; e < 8; ++e) { const float d = v[e] - mu; vs += d * d; }
  vs = wave_sum(vs);
  const float rstd = rsqrtf(vs * (1.0f / 512.0f) + 1e-5f);
  const float4 g1 = *(const float4*)&g[e0];
  const float4 g2 = *(const float4*)&g[e0 + 4];
  const float4 b1 = *(const float4*)&b[e0];
  const float4 b2 = *(const float4*)&b[e0 + 4];
  float y[8];
  y[0] = (v[0] - mu) * rstd * g1.x + b1.x; y[1] = (v[1] - mu) * rstd * g1.y + b1.y;
  y[2] = (v[2] - mu) * rstd * g1.z + b1.z; y[3] = (v[3] - mu) * rstd * g1.w + b1.w;
  y[4] = (v[4] - mu) * rstd * g2.x + b2.x; y[5] = (v[5] - mu) * rstd * g2.y + b2.y;
  y[6] = (v[6] - mu) * rstd * g2.z + b2.z; y[7] = (v[7] - mu) * rstd * g2.w + b2.w;
  if (FINAL) {
    const int l = t >> 6, n = t & 63;
    const int bb = l >> 6, wh = (l >> 3) & 7, ww = l & 7;
    const int pi = n >> 3, pj = n & 7;
    const int xrow = (bb * 4096 + (wh * 8 + pi) * 64 + (ww * 8 + pj)) * 512;
    *(float4*)&out32[xrow + e0] = make_float4(y[0], y[1], y[2], y[3]);
    *(float4*)&out32[xrow + e0 + 4] = make_float4(y[4], y[5], y[6], y[7]);
  } else {
    half8 o16;
#pragma unroll
    for (int e = 0; e < 8; ++e) o16[e] = (_Float16)y[e];
    *(half8*)&out16[trow + e0] = o16;
  }
}

// ---------------------------------------------------------------------------
extern "C" void kernel_launch(void* const* d_in, const int* in_sizes, int n_in,
                              void* d_out, int out_size, void* d_ws, size_t ws_size,
                              hipStream_t stream) {
  const float* x    = (const float*)d_in[0];
  const float* ipw  = (const float*)d_in[1];
  const float* ipb  = (const float*)d_in[2];
  const float* outw = (const float*)d_in[3];
  const float* outb = (const float*)d_in[4];
  const float* ln1g = (const float*)d_in[5];
  const float* ln1b = (const float*)d_in[6];
  const float* w1   = (const float*)d_in[7];
  const float* b1   = (const float*)d_in[8];
  const float* w2   = (const float*)d_in[9];
  const float* b2   = (const float*)d_in[10];
  const float* ln2g = (const float*)d_in[11];
  const float* ln2b = (const float*)d_in[12];
  float* out = (float*)d_out;
  char* ws = (char*)d_ws;

  _Float16* wqkv_h = (_Float16*)(ws + 0);          // 1536x512
  _Float16* wout_h = (_Float16*)(ws + 1572864);    // 512x512
  _Float16* w1_h   = (_Float16*)(ws + 2097152);    // 2048x512
  _Float16* w2_h   = (_Float16*)(ws + 4194304);    // 512x2048
  _Float16* xw_h   = (_Float16*)(ws + 6291456);    // 16384x512  (reused: y16)
  _Float16* qkv_h  = (_Float16*)(ws + 23068672);   // 16384x1536 (reused: h 16384x2048)
  _Float16* attn_h = (_Float16*)(ws + 90177536);   // 16384x512  (reused: f)
  _Float16* ao_h   = (_Float16*)(ws + 106954752);  // 16384x512
  _Float16* h_h = qkv_h;
  _Float16* f_h = attn_h;
  _Float16* y16 = xw_h;

  pre_kernel<<<7168, 256, 0, stream>>>(x, xw_h, ipw, wqkv_h, outw, wout_h,
                                       w1, w1_h, w2, w2_h);
  gemml_kernel<0, 512, 128, 4><<<1536, 256, 0, stream>>>(xw_h, wqkv_h, ipb, qkv_h, 1536);
  attn_kernel<<<1024, 256, 0, stream>>>(qkv_h, attn_h);
  gemml_kernel<0, 512, 64, 2><<<1024, 256, 0, stream>>>(attn_h, wout_h, outb, ao_h, 512);
  ln_kernel<0><<<4096, 256, 0, stream>>>(xw_h, ao_h, ln1g, ln1b, nullptr, y16);
  gemml_kernel<1, 512, 128, 4><<<2048, 256, 0, stream>>>(y16, w1_h, b1, h_h, 2048);
  gemml_kernel<0, 2048, 64, 4><<<512, 256, 0, stream>>>(h_h, w2_h, b2, f_h, 512);
  ln_kernel<1><<<4096, 256, 0, stream>>>(y16, f_h, ln2g, ln2b, out, nullptr);
}